// Round 16
// baseline (238.295 us; speedup 1.0000x reference)
//
#include <hip/hip_runtime.h>
#include <cstdint>
#include <cstddef>

typedef unsigned short u16t;
typedef __bf16 bf16x8_t __attribute__((ext_vector_type(8)));
typedef float f32x4_t __attribute__((ext_vector_type(4)));
typedef float f32x16_t __attribute__((ext_vector_type(16)));

#define MFMA32 __builtin_amdgcn_mfma_f32_32x32x16_bf16

__device__ __forceinline__ u16t f2bf(float f) {
    uint32_t u = __builtin_bit_cast(uint32_t, f);
    u += 0x7fffu + ((u >> 16) & 1u);   // RNE
    return (u16t)(u >> 16);
}

__device__ __forceinline__ uint32_t pk2bf(float a, float b) {
    return (uint32_t)f2bf(a) | ((uint32_t)f2bf(b) << 16);
}

__device__ __forceinline__ float bflo(uint32_t u) {
    return __builtin_bit_cast(float, u << 16);
}
__device__ __forceinline__ float bfhi(uint32_t u) {
    return __builtin_bit_cast(float, u & 0xffff0000u);
}

__device__ __forceinline__ bf16x8_t ld_frag(const u16t* p) {
    return __builtin_bit_cast(bf16x8_t, *(const uint4*)p);
}

// single-instruction RNE pack of two f32 -> bf16x2
__device__ __forceinline__ uint32_t cvtpk(float lo, float hi) {
    uint32_t r;
    asm("v_cvt_pk_bf16_f32 %0, %1, %2" : "=v"(r) : "v"(lo), "v"(hi));
    return r;
}
// a[32:63] <-> b[0:31]  (gfx950 v_permlane32_swap_b32)
__device__ __forceinline__ void swap32(uint32_t& a, uint32_t& b) {
    asm("v_permlane32_swap_b32 %0, %1" : "+v"(a), "+v"(b));
}

// async global->LDS DMA, 16 B per lane. lds base must be wave-uniform;
// lane i deposits at lds + i*16 B. Swizzling is done on the GLOBAL address.
__device__ __forceinline__ void gl_lds16(const u16t* g, u16t* l) {
    __builtin_amdgcn_global_load_lds(
        (const __attribute__((address_space(1))) void*)g,
        (__attribute__((address_space(3))) void*)l, 16, 0, 0);
}

// ---------------- fused cast f32 -> bf16 for x and ctx, 4 elems/thread ----------------
__global__ void cast2_bf16_kernel(const float* __restrict__ s0, u16t* __restrict__ d0, int n0,
                                  const float* __restrict__ s1, u16t* __restrict__ d1, int n1) {
    int i = blockIdx.x * blockDim.x + threadIdx.x;
    const float* s; u16t* d;
    if (i < n0) { s = s0; d = d0; }
    else { i -= n0; if (i >= n1) return; s = s1; d = d1; }
    float4 v = ((const float4*)s)[i];
    uint2 o;
    o.x = pk2bf(v.x, v.y);
    o.y = pk2bf(v.z, v.w);
    ((uint2*)d)[i] = o;
}

// ---------------- fused transpose+cast of all 4 weights: W[K][1024] -> Wt[1024][K] ----
__global__ void transpose4_kernel(const float* __restrict__ Wq, const float* __restrict__ Wk,
                                  const float* __restrict__ Wv, const float* __restrict__ Wo,
                                  u16t* __restrict__ Wqt, u16t* __restrict__ Wkt,
                                  u16t* __restrict__ Wvt, u16t* __restrict__ Wot) {
    const int z = blockIdx.z;
    const float* W = z == 0 ? Wq : (z == 1 ? Wk : (z == 2 ? Wv : Wo));
    u16t* Wt      = z == 0 ? Wqt : (z == 1 ? Wkt : (z == 2 ? Wvt : Wot));
    const int K   = (z == 1 || z == 2) ? 768 : 1024;
    const int N = 1024;
    int n0 = blockIdx.x * 32, k0 = blockIdx.y * 32;
    if (k0 >= K) return;
    __shared__ float tile[32][33];
    int tx = threadIdx.x, ty = threadIdx.y;
    for (int i = ty; i < 32; i += 8)
        tile[i][tx] = W[(size_t)(k0 + i) * N + n0 + tx];
    __syncthreads();
    for (int i = ty; i < 32; i += 8)
        Wt[(size_t)(n0 + i) * K + k0 + tx] = f2bf(tile[tx][i]);
}

// ---------------- qkv128: 128x128-tile MFMA32 QKV projections (proven R10) ----------------
__global__ __launch_bounds__(256, 2) void qkv128_kernel(
    const u16t* __restrict__ x_bf, const u16t* __restrict__ ctx_bf,
    const u16t* __restrict__ Wqt, const u16t* __restrict__ Wkt,
    const u16t* __restrict__ Wvt,
    u16t* __restrict__ Qh, u16t* __restrict__ Kh, u16t* __restrict__ Vt,
    float qscale)
{
    extern __shared__ __align__(16) u16t sm[];  // u16 units: A[2][8192] at 0, B[2][8192] at 16384
    const int z = blockIdx.z;
    const u16t* A  = (z == 0) ? x_bf : ctx_bf;
    const u16t* Bt = (z == 0) ? Wqt : ((z == 1) ? Wkt : Wvt);
    const int K    = (z == 0) ? 1024 : 768;
    const float sc = (z == 0) ? qscale : 1.0f;
    const int m0 = blockIdx.y * 128;
    const int h  = blockIdx.x;                  // n0 = h*128

    const int tid = threadIdx.x;
    const int wave = tid >> 6, lane = tid & 63;
    const int l31 = lane & 31, hh = lane >> 5;
    const int wm = wave & 1, wn = wave >> 1;
    const bool aRole = wave < 2;
    const int wh = wave & 1;
    const int rS = lane >> 3, cS = lane & 7;    // staging: 8 rows x 8 chunks per issue

    const int nk = K >> 6;
    const u16t* G  = aRole ? A : Bt;
    const int base = aRole ? m0 : h * 128;
    u16t* dstb     = sm + (aRole ? 0 : 16384);

    // ---- prologue: stage A[*][0:64], B[*][0:64] into buf 0 ----
#pragma unroll
    for (int it = 0; it < 8; ++it) {
        int is = wh * 8 + it;
        int rowL = is * 8 + rS;
        gl_lds16(&G[(size_t)(base + rowL) * K + ((cS ^ ((rowL ^ (rowL >> 3)) & 7)) * 8)],
                 dstb + is * 512);
    }

    f32x16_t acc[2][2];
#pragma unroll
    for (int i = 0; i < 2; ++i)
#pragma unroll
        for (int j = 0; j < 2; ++j)
#pragma unroll
            for (int r = 0; r < 16; ++r) acc[i][j][r] = 0.f;

    for (int ki = 0; ki < nk; ++ki) {
        const int buf = ki & 1;
        __syncthreads();

        if (ki + 1 < nk) {
            const int kc = (ki + 1) << 6;
            u16t* dst = dstb + (buf ^ 1) * 8192;
#pragma unroll
            for (int it = 0; it < 8; ++it) {
                int is = wh * 8 + it;
                int rowL = is * 8 + rS;
                gl_lds16(&G[(size_t)(base + rowL) * K + kc + ((cS ^ ((rowL ^ (rowL >> 3)) & 7)) * 8)],
                         dst + is * 512);
            }
        }

        const u16t* As = sm + buf * 8192;
        const u16t* Bs = sm + 16384 + buf * 8192;
        __builtin_amdgcn_s_setprio(1);
#pragma unroll
        for (int s = 0; s < 4; ++s) {
            bf16x8_t af[2], bfr[2];
#pragma unroll
            for (int i = 0; i < 2; ++i) {
                int r = wm * 64 + i * 32 + l31;
                af[i] = ld_frag(&As[r * 64 + (((s * 2 + hh) ^ ((r ^ (r >> 3)) & 7)) * 8)]);
            }
#pragma unroll
            for (int j = 0; j < 2; ++j) {
                int r = wn * 64 + j * 32 + l31;
                bfr[j] = ld_frag(&Bs[r * 64 + (((s * 2 + hh) ^ ((r ^ (r >> 3)) & 7)) * 8)]);
            }
#pragma unroll
            for (int i = 0; i < 2; ++i)
#pragma unroll
                for (int j = 0; j < 2; ++j)
                    acc[i][j] = MFMA32(af[i], bfr[j], acc[i][j], 0, 0, 0);
        }
        __builtin_amdgcn_s_setprio(0);
    }

    // ---- epilogue (MFMA32 C/D: col = l31, row = (g&3) + 8*(g>>2) + 4*hh) ----
    if (z != 2) {
        u16t* out = (z == 0) ? Qh : Kh;
#pragma unroll
        for (int i = 0; i < 2; ++i)
#pragma unroll
            for (int j = 0; j < 2; ++j) {
                int d = wn * 64 + j * 32 + l31;
#pragma unroll
                for (int g = 0; g < 16; ++g) {
                    int m = m0 + wm * 64 + i * 32 + (g & 3) + 8 * (g >> 2) + 4 * hh;
                    out[((size_t)h * 4096 + m) * 128 + d] = f2bf(acc[i][j][g] * sc);
                }
            }
    } else {
#pragma unroll
        for (int i = 0; i < 2; ++i)
#pragma unroll
            for (int j = 0; j < 2; ++j) {
                int d = wn * 64 + j * 32 + l31;
                size_t vb = ((size_t)h * 128 + d) * 4096 + m0 + wm * 64 + i * 32;
#pragma unroll
                for (int gq = 0; gq < 4; ++gq) {
                    uint2 pk;
                    pk.x = pk2bf(acc[i][j][gq * 4 + 0], acc[i][j][gq * 4 + 1]);
                    pk.y = pk2bf(acc[i][j][gq * 4 + 2], acc[i][j][gq * 4 + 3]);
                    *(uint2*)&Vt[vb + gq * 8 + 4 * hh] = pk;
                }
            }
    }
}

// ---------------- gemm_out: final projection, 128x128 tile, 8 waves (2 waves/SIMD) ----------------
// Same proven machinery (BK=64 dbuf, gl_lds16, swizzle g(r)=(r^(r>>3))&7, 0 conflicts).
// 512 threads, wave grid 2x4: each wave owns 64x32 output (acc 2 x f32x16 = 32 VGPR).
// Grid (8,32) = 256 blocks = 1 block/CU, 8 waves = 2 waves/SIMD (avoids v6's trap).
// Epilogue: f32 out[m*1024+c] = acc + bias[c], coalesced over l31.
__global__ __launch_bounds__(512, 2) void gemm_out_kernel(
    const u16t* __restrict__ A, const u16t* __restrict__ Bt,
    float* __restrict__ out, const float* __restrict__ bias)
{
    extern __shared__ __align__(16) u16t sm[];  // A[2][8192] @0, B[2][8192] @16384
    const int K = 1024, nk = 16;
    const int m0 = blockIdx.y * 128, n0 = blockIdx.x * 128;
    const int tid = threadIdx.x;
    const int wave = tid >> 6, lane = tid & 63;
    const int l31 = lane & 31, hh = lane >> 5;
    const int wm = wave & 1, wn = wave >> 1;    // wn 0..3
    const bool aRole = wave < 4;
    const int wq = wave & 3;
    const int rS = lane >> 3, cS = lane & 7;

    const u16t* G  = aRole ? A : Bt;
    const int base = aRole ? m0 : n0;
    u16t* dstb     = sm + (aRole ? 0 : 16384);

    // ---- prologue: stage both 128x64 panels into buf 0 (4 issues/wave) ----
#pragma unroll
    for (int it = 0; it < 4; ++it) {
        int is = wq * 4 + it;
        int rowL = is * 8 + rS;
        gl_lds16(&G[(size_t)(base + rowL) * K + ((cS ^ ((rowL ^ (rowL >> 3)) & 7)) * 8)],
                 dstb + is * 512);
    }

    f32x16_t acc[2];
#pragma unroll
    for (int i = 0; i < 2; ++i)
#pragma unroll
        for (int r = 0; r < 16; ++r) acc[i][r] = 0.f;

    for (int ki = 0; ki < nk; ++ki) {
        const int buf = ki & 1;
        __syncthreads();

        if (ki + 1 < nk) {
            const int kc = (ki + 1) << 6;
            u16t* dst = dstb + (buf ^ 1) * 8192;
#pragma unroll
            for (int it = 0; it < 4; ++it) {
                int is = wq * 4 + it;
                int rowL = is * 8 + rS;
                gl_lds16(&G[(size_t)(base + rowL) * K + kc + ((cS ^ ((rowL ^ (rowL >> 3)) & 7)) * 8)],
                         dst + is * 512);
            }
        }

        const u16t* As = sm + buf * 8192;
        const u16t* Bs = sm + 16384 + buf * 8192;
        __builtin_amdgcn_s_setprio(1);
#pragma unroll
        for (int s = 0; s < 4; ++s) {
            int rb = wn * 32 + l31;
            bf16x8_t bfr = ld_frag(&Bs[rb * 64 + (((s * 2 + hh) ^ ((rb ^ (rb >> 3)) & 7)) * 8)]);
#pragma unroll
            for (int i = 0; i < 2; ++i) {
                int ra = wm * 64 + i * 32 + l31;
                bf16x8_t af = ld_frag(&As[ra * 64 + (((s * 2 + hh) ^ ((ra ^ (ra >> 3)) & 7)) * 8)]);
                acc[i] = MFMA32(af, bfr, acc[i], 0, 0, 0);
            }
        }
        __builtin_amdgcn_s_setprio(0);
    }

    // ---- epilogue: f32 + bias (C/D: col = l31, row = (g&3)+8*(g>>2)+4*hh) ----
    const int c = n0 + wn * 32 + l31;
    const float b = bias[c];
#pragma unroll
    for (int i = 0; i < 2; ++i)
#pragma unroll
        for (int g = 0; g < 16; ++g) {
            int m = m0 + wm * 64 + i * 32 + (g & 3) + 8 * (g >> 2) + 4 * hh;
            out[(size_t)m * 1024 + c] = acc[i][g] + b;
        }
}

// ---------------- flash attention v11 (verbatim; proven 78.7 us, 0 conflicts) ----------------
__global__ __launch_bounds__(256, 2) void flash_kernel(
    const u16t* __restrict__ Qh, const u16t* __restrict__ Kh,
    const u16t* __restrict__ Vtg, u16t* __restrict__ Op0,
    u16t* __restrict__ Op1, float* __restrict__ lp)
{
    extern __shared__ __align__(16) u16t smem[];   // 65536 B
    const int h = blockIdx.y;
    const int q0 = blockIdx.x * 128;
    const int z = blockIdx.z;
    const int tid = threadIdx.x;
    const int wave = tid >> 6, lane = tid & 63;
    const int l31 = lane & 31, hh = lane >> 5;
    const int NT = 32;                              // 2048 k per z-split / 64

    const u16t* Kg = Kh + (size_t)h * 4096 * 128 + (size_t)z * 2048 * 128;
    const u16t* Vg = Vtg + (size_t)h * 128 * 4096 + z * 2048;

    // ---- stage Q (128 x 128) swizzled into smem, build qf (8 frags = wave's 32 q) ----
    {
        const u16t* Qg = Qh + ((size_t)h * 4096 + q0) * 128;
#pragma unroll
        for (int it = 0; it < 8; ++it) {
            int slot = it * 256 + tid;
            int r = slot >> 4, c = slot & 15;
            uint4 v = *(const uint4*)&Qg[(size_t)r * 128 + c * 8];
            *(uint4*)&smem[r * 128 + ((c ^ (r & 15)) * 8)] = v;
        }
    }
    __syncthreads();
    bf16x8_t qf[8];
    {
        int r = wave * 32 + l31;
#pragma unroll
        for (int s = 0; s < 8; ++s)
            qf[s] = ld_frag(&smem[r * 128 + (((s * 2 + hh) ^ (r & 15)) * 8)]);
    }
    __syncthreads();   // all waves done reading Q before DMA overwrites

    // DMA roles: waves 0,1 stage K (64x128, 8 issues each), waves 2,3 stage V^T (128x64)
    const bool kRole = wave < 2;
    const int wh = wave & 1;
    const int rK = lane >> 4, cK = lane & 15;   // K: 4 rows x 16 chunks (256B rows)
    const int rV = lane >> 3, cV = lane & 7;    // V: 8 rows x 8 chunks (128B rows)

    // ---- prologue: K[0] -> kslot0 (V[0] is issued inside the loop at t=0) ----
    if (kRole) {
#pragma unroll
        for (int it = 0; it < 8; ++it) {
            int is = wh * 8 + it;
            int rowL = is * 4 + rK;
            gl_lds16(Kg + (size_t)rowL * 128 + ((cK ^ (rowL & 15)) * 8),
                     smem + is * 512);
        }
    }

    f32x16_t Ow[4];
#pragma unroll
    for (int dg = 0; dg < 4; ++dg)
#pragma unroll
        for (int r = 0; r < 16; ++r) Ow[dg][r] = 0.f;

    float lsum = 0.f;
    const int swzk = l31 & 15;
    bf16x8_t pf[4];            // P of tile t-1 (k-slices 0..3), consumed at iter t

    for (int t = 0; t <= NT; ++t) {
        __syncthreads();   // drains each wave's own DMA: K[t] (issued t-1), V[t-1] (issued t-1)

        // ---- issue DMA: V-role stages V[t] (used at t+1); K-role stages K[t+1] ----
        if (kRole) {
            if (t + 1 < NT) {
                const int j0 = (t + 1) * 64;
                u16t* kd = smem + ((t + 1) & 1) * 8192;
#pragma unroll
                for (int it = 0; it < 8; ++it) {
                    int is = wh * 8 + it;
                    int rowL = is * 4 + rK;
                    gl_lds16(Kg + (size_t)(j0 + rowL) * 128 + ((cK ^ (rowL & 15)) * 8),
                             kd + is * 512);
                }
            }
        } else {
            if (t < NT) {
                const int j0 = t * 64;
                u16t* vd = smem + 16384 + (t & 1) * 8192;
#pragma unroll
                for (int it = 0; it < 8; ++it) {
                    int is = wh * 8 + it;
                    int rowL = is * 8 + rV;
                    gl_lds16(Vg + (size_t)rowL * 4096 + j0 + ((cV ^ ((rowL ^ (rowL >> 3)) & 7)) * 8),
                             vd + is * 512);
                }
            }
        }

        __builtin_amdgcn_s_setprio(1);
        // ---- QK^T[t]: two 32x32 S-tiles (k 0-31, 32-63), K-frags row l31 / 32+l31 ----
        f32x16_t St0, St1;
#pragma unroll
        for (int r = 0; r < 16; ++r) { St0[r] = 0.f; St1[r] = 0.f; }
        if (t < NT) {
            const u16t* kb = smem + (t & 1) * 8192;
#pragma unroll
            for (int s = 0; s < 8; ++s) {
                int ch = ((s * 2 + hh) ^ swzk) * 8;
                bf16x8_t k0 = ld_frag(&kb[l31 * 128 + ch]);
                bf16x8_t k1 = ld_frag(&kb[(32 + l31) * 128 + ch]);
                St0 = MFMA32(k0, qf[s], St0, 0, 0, 0);
                St1 = MFMA32(k1, qf[s], St1, 0, 0, 0);
            }
        }
        // ---- PV[t-1]: V^T (vslot (t-1)&1) x pf (registers from last iter) ----
        if (t >= 1) {
            const u16t* vb = smem + 16384 + ((t - 1) & 1) * 8192;
#pragma unroll
            for (int dg = 0; dg < 4; ++dg) {
                int rv = dg * 32 + l31;
                int gsw = (rv ^ (rv >> 3)) & 7;
#pragma unroll
                for (int sl = 0; sl < 4; ++sl) {
                    bf16x8_t vf = ld_frag(&vb[rv * 64 + (((sl * 2 + hh) ^ gsw) * 8)]);
                    Ow[dg] = MFMA32(vf, pf[sl], Ow[dg], 0, 0, 0);
                }
            }
        }
        __builtin_amdgcn_s_setprio(0);

        // ---- softmax[t] -> pf[0..3] for next iter's PV ----
        if (t < NT) {
#pragma unroll
            for (int half = 0; half < 2; ++half) {
                float p[16];
#pragma unroll
                for (int r = 0; r < 16; ++r)
                    p[r] = __builtin_amdgcn_exp2f(half ? St1[r] : St0[r]);
                lsum += ((((p[0] + p[1]) + (p[2] + p[3])) + ((p[4] + p[5]) + (p[6] + p[7])))
                      + (((p[8] + p[9]) + (p[10] + p[11])) + ((p[12] + p[13]) + (p[14] + p[15]))));
                uint32_t w0 = cvtpk(p[0], p[1]),   w2 = cvtpk(p[4], p[5]);
                uint32_t w1 = cvtpk(p[2], p[3]),   w3 = cvtpk(p[6], p[7]);
                swap32(w0, w2); swap32(w1, w3);    // words for even k-slice
                uint32_t y0 = cvtpk(p[8], p[9]),   y2 = cvtpk(p[12], p[13]);
                uint32_t y1 = cvtpk(p[10], p[11]), y3 = cvtpk(p[14], p[15]);
                swap32(y0, y2); swap32(y1, y3);    // words for odd k-slice
                uint4 pw0; pw0.x = w0; pw0.y = w1; pw0.z = w2; pw0.w = w3;
                uint4 pw1; pw1.x = y0; pw1.y = y1; pw1.z = y2; pw1.w = y3;
                pf[half * 2 + 0] = __builtin_bit_cast(bf16x8_t, pw0);
                pf[half * 2 + 1] = __builtin_bit_cast(bf16x8_t, pw1);
            }
        }
    }

    // ---- epilogue: reduce l across halves, store UNNORMALIZED partials ----
    lsum += __shfl_xor(lsum, 32, 64);
    u16t* Op = z ? Op1 : Op0;
    size_t i = (size_t)(q0 + wave * 32 + l31);
    if (hh == 0) lp[z * 32768 + i * 8 + h] = lsum;
#pragma unroll
    for (int dg = 0; dg < 4; ++dg)
#pragma unroll
        for (int g = 0; g < 4; ++g) {
            uint2 pk;
            pk.x = pk2bf(Ow[dg][g * 4 + 0], Ow[dg][g * 4 + 1]);
            pk.y = pk2bf(Ow[dg][g * 4 + 2], Ow[dg][g * 4 + 3]);
            *(uint2*)&Op[i * 1024 + h * 128 + dg * 32 + g * 8 + hh * 4] = pk;
        }
}

// ---------------- combine: Oh = (O0 + O1) / (l0 + l1), 8 bf16/thread ----------------
__global__ __launch_bounds__(256) void combine_kernel(
    const u16t* __restrict__ O0, const u16t* __restrict__ O1,
    const float* __restrict__ lp, u16t* __restrict__ out)
{
    int t = blockIdx.x * blockDim.x + threadIdx.x;
    int e = t << 3;
    int i = e >> 10, h = (e >> 7) & 7;
    float inv = 1.f / (lp[i * 8 + h] + lp[32768 + i * 8 + h]);
    uint4 a = ((const uint4*)O0)[t];
    uint4 b = ((const uint4*)O1)[t];
    uint4 r;
    r.x = pk2bf((bflo(a.x) + bflo(b.x)) * inv, (bfhi(a.x) + bfhi(b.x)) * inv);
    r.y = pk2bf((bflo(a.y) + bflo(b.y)) * inv, (bfhi(a.y) + bfhi(b.y)) * inv);
    r.z = pk2bf((bflo(a.z) + bflo(b.z)) * inv, (bfhi(a.z) + bfhi(b.z)) * inv);
    r.w = pk2bf((bflo(a.w) + bflo(b.w)) * inv, (bfhi(a.w) + bfhi(b.w)) * inv);
    ((uint4*)out)[t] = r;
}

// =====================================================================
extern "C" void kernel_launch(void* const* d_in, const int* in_sizes, int n_in,
                              void* d_out, int out_size, void* d_ws, size_t ws_size,
                              hipStream_t stream)
{
    (void)in_sizes; (void)n_in; (void)out_size; (void)ws_size;
    const float* x    = (const float*)d_in[0];   // (2,2048,1024)
    const float* ctx  = (const float*)d_in[1];   // (2,2048,768)
    const float* Wq   = (const float*)d_in[2];   // (1024,1024)
    const float* Wk   = (const float*)d_in[3];   // (768,1024)
    const float* Wv   = (const float*)d_in[4];   // (768,1024)
    const float* Wout = (const float*)d_in[5];   // (1024,1024)
    const float* bout = (const float*)d_in[6];   // (1024,)
    float* out = (float*)d_out;                  // (2,2048,1024) f32

    u16t* ws = (u16t*)d_ws;                      // ~47 MB of bf16 scratch
    u16t* x_bf   = ws;                           // 4194304
    u16t* ctx_bf = x_bf + 4194304;               // 3145728
    u16t* Wqt    = ctx_bf + 3145728;             // 1048576  [N=1024][K=1024]
    u16t* Wkt    = Wqt + 1048576;                // 786432   [1024][768]
    u16t* Wvt    = Wkt + 786432;                 // 786432
    u16t* Woutt  = Wvt + 786432;                 // 1048576
    u16t* Qh     = Woutt + 1048576;              // 4194304  [8][4096][128]
    u16t* Kh     = Qh + 4194304;                 // 4194304
    u16t* Vt     = Kh + 4194304;                 // 4194304  [8][128][4096]
    // flash-phase reuse of dead projection buffers:
    u16t* Oh   = x_bf;                           // split-0 partial, then combined O
    u16t* Ohp1 = ws + 4194304;                   // split-1 partial (over ctx_bf+Wqt, dead)
    float* lp  = (float*)(ws + 8388608);         // l partials [2][4096][8] (over Wkt, dead)

    // tau * dim^-0.5 * log2(e), folded into Q so flash uses raw exp2
    constexpr float QSCALE = 1.5f * 0.08838834764831845f * 1.4426950408889634f;

    (void)hipFuncSetAttribute((const void*)flash_kernel,
                              hipFuncAttributeMaxDynamicSharedMemorySize, 65536);
    (void)hipFuncSetAttribute((const void*)qkv128_kernel,
                              hipFuncAttributeMaxDynamicSharedMemorySize, 65536);
    (void)hipFuncSetAttribute((const void*)gemm_out_kernel,
                              hipFuncAttributeMaxDynamicSharedMemorySize, 65536);

    cast2_bf16_kernel<<<7168, 256, 0, stream>>>(x, x_bf, 1048576, ctx, ctx_bf, 786432);
    transpose4_kernel<<<dim3(32, 32, 4), dim3(32, 8), 0, stream>>>(
        Wq, Wk, Wv, Wout, Wqt, Wkt, Wvt, Woutt);

    // grid: x = head/N-tile (8), y = M-tile (32), z = {Q,K,V}
    qkv128_kernel<<<dim3(8, 32, 3), 256, 65536, stream>>>(
        x_bf, ctx_bf, Wqt, Wkt, Wvt, Qh, Kh, Vt, QSCALE);

    // grid: x = q-block (128 rows), y = head, z = k-split; 512 blocks = 2 per CU
    flash_kernel<<<dim3(32, 8, 2), 256, 65536, stream>>>(Qh, Kh, Vt, Oh, Ohp1, lp);
    combine_kernel<<<2048, 256, 0, stream>>>(Oh, Ohp1, lp, Oh);

    // final projection: 128x128 tiles, 8 waves/block, 256 blocks = 2 waves/SIMD
    gemm_out_kernel<<<dim3(8, 32), 512, 65536, stream>>>(Oh, Woutt, out, bout);
}